// Round 6
// baseline (54009.863 us; speedup 1.0000x reference)
//
#include <hip/hip_runtime.h>

// TimeVAEDecoder: B=128, LAT=128, H=512, F=128, L=256, NL=2
// Round 6: LDS-RESIDENT WEIGHTS persistent kernel. R5 counters showed 5.4 GB
// HBM fetch/dispatch (21 MB/step = full weight re-fetch; per-XCD L2 working
// set 5.4 MB > 4 MB thrashed). Now each block permanently owns an N=16 weight
// slice (4 h-cols x 4 gates, gate-interleaved) in LDS (96 KB, lane-order,
// conflict-free), computing all M=128 rows against it:
//   blocks 0..127: cell0 (WAf), blocks 128..255: cell1 (WBf)
//   idle half during phase A does ys tiles; W_pre/W_out stay in L2.
// Numerics identical to rounds 3-5 (3-plane split, 6 MFMA products, two-pass
// LN) -> absmax pedigree 0.066.

typedef unsigned int uint32;
typedef unsigned short u16;
typedef __attribute__((ext_vector_type(8))) short bf16x8;
typedef __attribute__((ext_vector_type(4))) float f32x4;

static constexpr int Ln = 256, Fn = 128;
static constexpr int APS = 65536;    // activation plane stride (elems): 128x512
static constexpr int WPS = 2097152;  // cell-weight plane stride: 2048x1024
static constexpr int OPS = 65536;    // W_out plane stride: 128x512
static constexpr int PPS = 262144;   // W_pre plane stride: 512x512

__device__ __forceinline__ u16 f2bf(float f) {
  union { float f; uint32 u; } v; v.f = f;
  uint32 u = v.u + 0x7fffu + ((v.u >> 16) & 1u);
  return (u16)(u >> 16);
}
__device__ __forceinline__ float bf2f(u16 h) {
  union { uint32 u; float f; } v; v.u = ((uint32)h) << 16;
  return v.f;
}
__device__ __forceinline__ void splitbf3(float v, u16* hi, u16* mid, u16* lo) {
  u16 h = f2bf(v);
  float r = v - bf2f(h);
  u16 m = f2bf(r);
  float r2 = r - bf2f(m);
  *hi = h; *mid = m; *lo = f2bf(r2);
}
__device__ __forceinline__ float sigm(float x) { return 1.f / (1.f + expf(-x)); }
__device__ __forceinline__ bf16x8 ldf(const u16* p) { return *(const bf16x8*)p; }

#define MFMA1(A, B, ACC) ACC = __builtin_amdgcn_mfma_f32_16x16x32_bf16((A), (B), (ACC), 0, 0, 0)
// 6 products, 4 accumulators: A0+=hh; A1+=hm+mh; A2+=hl+mm; A3+=lh
#define MFMA6(AH, AM, AL, BH, BM, BL, A0, A1, A2, A3) \
  do {                                                \
    MFMA1(AH, BH, A0);                                \
    MFMA1(AH, BM, A1); MFMA1(AM, BH, A1);             \
    MFMA1(AH, BL, A2); MFMA1(AM, BM, A2);             \
    MFMA1(AL, BH, A3);                                \
  } while (0)

// ---------------- prep kernels (unchanged) ----------------

__global__ void prep_hc0(const float* __restrict__ z,
                         const float* __restrict__ W_l2h, const float* __restrict__ b_l2h,
                         const float* __restrict__ W_l2c, const float* __restrict__ b_l2c,
                         u16* __restrict__ ha0, u16* __restrict__ hb0,
                         float* __restrict__ ca, float* __restrict__ cb) {
  int idx = blockIdx.x * 256 + threadIdx.x;  // 131072
  int b = idx & 127, j = idx >> 7;
  float ah = b_l2h[j], ac = b_l2c[j];
  for (int k = 0; k < 128; ++k) {
    float zv = z[b * 128 + k];
    ah += zv * W_l2h[j * 128 + k];
    ac += zv * W_l2c[j * 128 + k];
  }
  int flat = b * 1024 + j;
  if (flat < 65536) {
    splitbf3(ah, &ha0[flat], &ha0[APS + flat], &ha0[2 * APS + flat]);
    ca[flat] = ac;
  } else {
    flat -= 65536;
    splitbf3(ah, &hb0[flat], &hb0[APS + flat], &hb0[2 * APS + flat]);
    cb[flat] = ac;
  }
}

__global__ void prep_zp(const float* __restrict__ z, const float* __restrict__ W_zp,
                        const float* __restrict__ b_zp, float* __restrict__ zp) {
  int idx = blockIdx.x * 256 + threadIdx.x;  // 65536
  int b = idx & 127, h = idx >> 7;
  float a = b_zp[h];
  for (int k = 0; k < 128; ++k) a += z[b * 128 + k] * W_zp[h * 128 + k];
  zp[b * 512 + h] = a;
}

__global__ void prep_gz(const float* __restrict__ zp, const float* __restrict__ W_ih0,
                        const float* __restrict__ b_ih0, const float* __restrict__ b_hh0,
                        const float* __restrict__ b_out,
                        float* __restrict__ GZ0, float* __restrict__ GZ1) {
  int idx = blockIdx.x * 256 + threadIdx.x;  // 262144
  int b = idx & 127, g = idx >> 7;
  const float* wr = W_ih0 + (size_t)g * 640;
  float a = b_ih0[g] + b_hh0[g];
  for (int k = 0; k < 512; ++k) a += zp[b * 512 + k] * wr[128 + k];
  float co = 0.f;
  for (int f = 0; f < 128; ++f) co += b_out[f] * wr[f];
  GZ0[b * 2048 + g] = a;
  GZ1[b * 2048 + g] = a + co;
}

__global__ void prep_waf(const float* __restrict__ W_out, const float* __restrict__ W_ih0,
                         const float* __restrict__ W_hh0, u16* __restrict__ WAf) {
  int idx = blockIdx.x * 256 + threadIdx.x;  // 2097152
  int k = idx & 1023, g = idx >> 10;
  float v;
  if (k < 512) {
    v = 0.f;
    const float* wr = W_ih0 + (size_t)g * 640;
    for (int f = 0; f < 128; ++f) v += W_out[f * 512 + k] * wr[f];
  } else {
    v = W_hh0[(size_t)g * 512 + (k - 512)];
  }
  splitbf3(v, &WAf[idx], &WAf[WPS + idx], &WAf[2 * WPS + idx]);
}

__global__ void prep_wbf(const float* __restrict__ W_ih1, const float* __restrict__ W_hh1,
                         u16* __restrict__ WBf) {
  int idx = blockIdx.x * 256 + threadIdx.x;  // 2097152
  int k = idx & 1023, g = idx >> 10;
  float v = (k < 512) ? W_ih1[(size_t)g * 512 + k] : W_hh1[(size_t)g * 512 + (k - 512)];
  splitbf3(v, &WBf[idx], &WBf[WPS + idx], &WBf[2 * WPS + idx]);
}

__global__ void prep_misc(const float* __restrict__ W_pre, const float* __restrict__ W_out,
                          const float* __restrict__ b_ih1, const float* __restrict__ b_hh1,
                          u16* __restrict__ WPf, u16* __restrict__ WOf,
                          float* __restrict__ gb1, u16* __restrict__ s,
                          uint32* __restrict__ barcnt) {
  int idx = blockIdx.x * 256 + threadIdx.x;
  if (idx < 262144) { splitbf3(W_pre[idx], &WPf[idx], &WPf[PPS + idx], &WPf[2 * PPS + idx]); return; }
  idx -= 262144;
  if (idx < 65536) { splitbf3(W_out[idx], &WOf[idx], &WOf[OPS + idx], &WOf[2 * OPS + idx]); return; }
  idx -= 65536;
  if (idx < 2048) { gb1[idx] = b_ih1[idx] + b_hh1[idx]; return; }
  idx -= 2048;
  if (idx < 196608) { s[idx] = 0; return; }
  idx -= 196608;
  if (idx < 8) barcnt[idx] = 0;
}

// ---------------- persistent kernel ----------------

__device__ __forceinline__ void gridbar(uint32* cnt, int tid) {
  __syncthreads();
  if (tid == 0) {
    uint32 old = __hip_atomic_fetch_add(cnt, 1u, __ATOMIC_ACQ_REL, __HIP_MEMORY_SCOPE_AGENT);
    uint32 target = (old / 256u + 1u) * 256u;
    while (__hip_atomic_load(cnt, __ATOMIC_ACQUIRE, __HIP_MEMORY_SCOPE_AGENT) < target)
      __builtin_amdgcn_s_sleep(8);
  }
  __syncthreads();
}

// Gates GEMM against LDS-resident N=16 slice: M=128, K=1024=[x0||x1].
// Wave w does M-tiles {w, w+4}. n = r16: gate=r16&3, j=r16>>2, h=ng*4+j.
__device__ __forceinline__ void gates2(
    const u16* __restrict__ x0, const u16* __restrict__ x1,
    const u16* wlds, const float* __restrict__ bias, int bias_stride,
    int ng, float* creg, u16* __restrict__ hout, int tid, float* gb2) {
  int lane = tid & 63, w = tid >> 6, q = lane >> 4, r16 = lane & 15;
  f32x4 acc[2][4];
#pragma unroll
  for (int m = 0; m < 2; ++m)
#pragma unroll
    for (int a = 0; a < 4; ++a) acc[m][a] = (f32x4){0.f, 0.f, 0.f, 0.f};
  const u16* a0r = x0 + (size_t)(w * 16 + r16) * 512 + q * 8;
  const u16* a1r = x0 + (size_t)((w + 4) * 16 + r16) * 512 + q * 8;
#pragma unroll 8
  for (int kb = 0; kb < 16; ++kb) {
    const u16* bp = wlds + kb * 512 + lane * 8;
    bf16x8 bh = *(const bf16x8*)bp;
    bf16x8 bm = *(const bf16x8*)(bp + 16384);
    bf16x8 bl = *(const bf16x8*)(bp + 32768);
    const u16* pa = a0r + kb * 32;
    bf16x8 ah = ldf(pa), am = ldf(pa + APS), al = ldf(pa + 2 * APS);
    MFMA6(ah, am, al, bh, bm, bl, acc[0][0], acc[0][1], acc[0][2], acc[0][3]);
    const u16* pb = a1r + kb * 32;
    bf16x8 ah1 = ldf(pb), am1 = ldf(pb + APS), al1 = ldf(pb + 2 * APS);
    MFMA6(ah1, am1, al1, bh, bm, bl, acc[1][0], acc[1][1], acc[1][2], acc[1][3]);
  }
  a0r = x1 + (size_t)(w * 16 + r16) * 512 + q * 8;
  a1r = x1 + (size_t)((w + 4) * 16 + r16) * 512 + q * 8;
#pragma unroll 8
  for (int kb = 0; kb < 16; ++kb) {
    const u16* bp = wlds + (16 + kb) * 512 + lane * 8;
    bf16x8 bh = *(const bf16x8*)bp;
    bf16x8 bm = *(const bf16x8*)(bp + 16384);
    bf16x8 bl = *(const bf16x8*)(bp + 32768);
    const u16* pa = a0r + kb * 32;
    bf16x8 ah = ldf(pa), am = ldf(pa + APS), al = ldf(pa + 2 * APS);
    MFMA6(ah, am, al, bh, bm, bl, acc[0][0], acc[0][1], acc[0][2], acc[0][3]);
    const u16* pb = a1r + kb * 32;
    bf16x8 ah1 = ldf(pb), am1 = ldf(pb + APS), al1 = ldf(pb + 2 * APS);
    MFMA6(ah1, am1, al1, bh, bm, bl, acc[1][0], acc[1][1], acc[1][2], acc[1][3]);
  }
#pragma unroll
  for (int m = 0; m < 2; ++m)
#pragma unroll
    for (int r = 0; r < 4; ++r)
      gb2[((w + m * 4) * 16 + q * 4 + r) * 17 + r16] =
          ((acc[m][3][r] + acc[m][2][r]) + acc[m][1][r]) + acc[m][0][r];
  __syncthreads();
#pragma unroll
  for (int o = 0; o < 2; ++o) {
    int oi = tid + o * 256;  // 0..511: b = oi>>2, j = oi&3
    int b = oi >> 2, j = oi & 3;
    int h = ng * 4 + j;
    const float* bb = bias + (size_t)b * bias_stride;  // 2048 (GZ) or 0 (gb1)
    float gi = gb2[b * 17 + j * 4 + 0] + bb[h];
    float gf = gb2[b * 17 + j * 4 + 1] + bb[512 + h];
    float gc = gb2[b * 17 + j * 4 + 2] + bb[1024 + h];
    float go = gb2[b * 17 + j * 4 + 3] + bb[1536 + h];
    float cn = sigm(gf) * creg[o] + sigm(gi) * tanhf(gc);
    creg[o] = cn;
    float hv = sigm(go) * tanhf(cn);
    int idx = b * 512 + h;
    splitbf3(hv, &hout[idx], &hout[APS + idx], &hout[2 * APS + idx]);
  }
}

// ys tile: 16 rows x 16 f-cols, 4 waves split K=512, W_out from L2.
__device__ __forceinline__ void ys_unit(
    const u16* __restrict__ sv, const u16* __restrict__ WOf,
    const float* __restrict__ b_out, float* __restrict__ ys,
    int t, int bg, int fh, int tid, float* gb4) {
  int lane = tid & 63, w = tid >> 6;
  int q = lane >> 4, r16 = lane & 15;
  int f0 = fh * 16, b0 = bg * 16;
  const u16* wr = WOf + (size_t)(f0 + r16) * 512 + w * 128 + q * 8;
  const u16* ar = sv + (size_t)(b0 + r16) * 512 + w * 128 + q * 8;
  f32x4 A0 = {0.f, 0.f, 0.f, 0.f}, A1 = A0, A2 = A0, A3 = A0;
#pragma unroll
  for (int kb = 0; kb < 4; ++kb) {
    bf16x8 ah = ldf(ar + kb * 32), am = ldf(ar + APS + kb * 32), al = ldf(ar + 2 * APS + kb * 32);
    bf16x8 bh = ldf(wr + kb * 32), bm = ldf(wr + OPS + kb * 32), bl = ldf(wr + 2 * OPS + kb * 32);
    MFMA6(ah, am, al, bh, bm, bl, A0, A1, A2, A3);
  }
#pragma unroll
  for (int r = 0; r < 4; ++r)
    gb4[(w * 16 + q * 4 + r) * 17 + r16] = ((A3[r] + A2[r]) + A1[r]) + A0[r];
  __syncthreads();
  int bl_ = tid >> 4, fl = tid & 15;
  float val = ((gb4[(3 * 16 + bl_) * 17 + fl] + gb4[(2 * 16 + bl_) * 17 + fl]) +
               gb4[(1 * 16 + bl_) * 17 + fl]) + gb4[(0 * 16 + bl_) * 17 + fl] + b_out[f0 + fl];
  ys[(size_t)(b0 + bl_) * (Ln * Fn) + (size_t)(t - 1) * Fn + f0 + fl] = val;
}

// LN(hb) -> pre = relu(ln@W_pre^T + b_pre) -> s = pre + ln (W_pre from L2)
__device__ __forceinline__ void lnpre_unit(
    const u16* __restrict__ hb, const u16* __restrict__ WPf,
    const float* __restrict__ lng, const float* __restrict__ lnb,
    const float* __restrict__ b_pre, u16* __restrict__ s_out,
    int jg, int bg, int tid, float* gb4,
    u16* lnH, u16* lnM, u16* lnL, float* red, float* smean, float* srstd) {
  int lane = tid & 63, w = tid >> 6;
  int q = lane >> 4, r16 = lane & 15;
  int j0 = jg * 16, b0 = bg * 16;
  int rl = tid >> 4, cg = tid & 15;
  float v[32];
  {
    const u16* hr = hb + (size_t)(b0 + rl) * 512 + cg * 32;
    float sm = 0.f;
#pragma unroll
    for (int kk = 0; kk < 32; ++kk) {
      v[kk] = (bf2f(hr[2 * APS + kk]) + bf2f(hr[APS + kk])) + bf2f(hr[kk]);
      sm += v[kk];
    }
    red[rl * 16 + cg] = sm;
  }
  __syncthreads();
  if (tid < 16) {
    float s1 = 0.f;
    for (int i = 0; i < 16; ++i) s1 += red[tid * 16 + i];
    smean[tid] = s1 * (1.f / 512.f);
  }
  __syncthreads();
  float m = smean[rl];
  {
    float sq = 0.f;
#pragma unroll
    for (int kk = 0; kk < 32; ++kk) { float d = v[kk] - m; sq += d * d; }
    red[rl * 16 + cg] = sq;
  }
  __syncthreads();
  if (tid < 16) {
    float s2 = 0.f;
    for (int i = 0; i < 16; ++i) s2 += red[tid * 16 + i];
    srstd[tid] = 1.f / sqrtf(s2 * (1.f / 512.f) + 1e-5f);
  }
  __syncthreads();
  float rs = srstd[rl];
#pragma unroll
  for (int kk = 0; kk < 32; ++kk) {
    int col = cg * 32 + kk;
    float lv = (v[kk] - m) * rs * lng[col] + lnb[col];
    splitbf3(lv, &lnH[rl * 520 + col], &lnM[rl * 520 + col], &lnL[rl * 520 + col]);
  }
  __syncthreads();
  const u16* wr = WPf + (size_t)(j0 + r16) * 512 + w * 128 + q * 8;
  const u16* aH = lnH + r16 * 520 + w * 128 + q * 8;
  const u16* aM = lnM + r16 * 520 + w * 128 + q * 8;
  const u16* aL = lnL + r16 * 520 + w * 128 + q * 8;
  f32x4 A0 = {0.f, 0.f, 0.f, 0.f}, A1 = A0, A2 = A0, A3 = A0;
#pragma unroll
  for (int kb = 0; kb < 4; ++kb) {
    bf16x8 ah = ldf(aH + kb * 32), am = ldf(aM + kb * 32), al = ldf(aL + kb * 32);
    bf16x8 bh = ldf(wr + kb * 32), bm = ldf(wr + PPS + kb * 32), bl = ldf(wr + 2 * PPS + kb * 32);
    MFMA6(ah, am, al, bh, bm, bl, A0, A1, A2, A3);
  }
#pragma unroll
  for (int r = 0; r < 4; ++r)
    gb4[(w * 16 + q * 4 + r) * 17 + r16] = ((A3[r] + A2[r]) + A1[r]) + A0[r];
  __syncthreads();
  int bl_ = tid >> 4, jl = tid & 15;
  int col = j0 + jl;
  float pre = ((gb4[(3 * 16 + bl_) * 17 + jl] + gb4[(2 * 16 + bl_) * 17 + jl]) +
               gb4[(1 * 16 + bl_) * 17 + jl]) + gb4[(0 * 16 + bl_) * 17 + jl] + b_pre[col];
  pre = fmaxf(pre, 0.f);
  float lnv = (bf2f(lnL[bl_ * 520 + col]) + bf2f(lnM[bl_ * 520 + col])) + bf2f(lnH[bl_ * 520 + col]);
  float sval = pre + lnv;
  size_t sidx = (size_t)(b0 + bl_) * 512 + col;
  splitbf3(sval, &s_out[sidx], &s_out[APS + sidx], &s_out[2 * APS + sidx]);
}

__global__ __launch_bounds__(256, 1) void persist_k(
    const u16* __restrict__ WAf, const u16* __restrict__ WBf,
    const u16* __restrict__ WPf, const u16* __restrict__ WOf,
    const float* __restrict__ GZ0, const float* __restrict__ GZ1,
    const float* __restrict__ gb1,
    const float* __restrict__ ca, const float* __restrict__ cb,
    u16* ha0, u16* ha1, u16* hb0, u16* hb1, u16* sbuf,
    const float* __restrict__ lng, const float* __restrict__ lnb,
    const float* __restrict__ b_pre, const float* __restrict__ b_out,
    float* __restrict__ out, uint32* barcnt) {
  extern __shared__ char smem[];          // 153728 B total
  u16* wlds = (u16*)smem;                 // 96 KB: 3 planes x [kb 0..31][lane][8]
  char* ub = smem + 98304;                // phase union
  float* gb2 = (float*)ub;                // gates epilogue [128][17] f32
  u16* lnH = (u16*)ub;                    // lnpre staging (aliases gb2)
  u16* lnM = lnH + 8320;
  u16* lnL = lnM + 8320;
  float* red = (float*)(ub + 49920);
  float* smean = (float*)(ub + 50944);
  float* srstd = (float*)(ub + 51008);
  float* gb4 = (float*)(ub + 51072);      // [4][16][17] f32
  int tid = threadIdx.x, blk = blockIdx.x;
  int grp = blk >> 7, ng = blk & 127;
  // stage this block's weight slice into LDS (lane-order, conflict-free)
  const u16* Wsrc = grp ? WBf : WAf;
  for (int i = tid; i < 49152; i += 256) {
    int p = i >> 14, rem = i & 16383;
    int kb = rem >> 9, l2 = (rem >> 3) & 63, e = rem & 7;
    int q2 = l2 >> 4, r2 = l2 & 15;
    int grow = (r2 & 3) * 512 + ng * 4 + (r2 >> 2);  // gate-interleaved n
    wlds[i] = Wsrc[(size_t)p * WPS + (size_t)grow * 1024 + kb * 32 + q2 * 8 + e];
  }
  __syncthreads();
  // cell state in registers: this block owns (all b) x (its 4 h)
  float creg[2];
  {
    const float* cs = grp ? cb : ca;
#pragma unroll
    for (int o = 0; o < 2; ++o) {
      int oi = tid + o * 256;
      creg[o] = cs[(oi >> 2) * 512 + ng * 4 + (oi & 3)];
    }
  }
  u16* haB[2] = {ha0, ha1};
  u16* hbB[2] = {hb0, hb1};
  for (int t = 0; t < Ln; ++t) {
    // phase A: cell0 blocks compute gates0([s||ha]); cell1 blocks 0..63 do ys[t-1]
    if (grp == 0) {
      gates2(sbuf, haB[t & 1], wlds, t ? GZ1 : GZ0, 2048, ng, creg,
             haB[(t + 1) & 1], tid, gb2);
    } else if (ng < 64 && t >= 1) {
      ys_unit(sbuf, WOf, b_out, out, t, ng >> 3, ng & 7, tid, gb4);
    }
    gridbar(barcnt, tid);
    // phase B: cell1 blocks compute gates1([ha'||hb])
    if (grp == 1) {
      gates2(haB[(t + 1) & 1], hbB[t & 1], wlds, gb1, 0, ng, creg,
             hbB[(t + 1) & 1], tid, gb2);
    }
    gridbar(barcnt, tid);
    // phase C: all 256 blocks: layernorm + pre + s'
    lnpre_unit(hbB[(t + 1) & 1], WPf, lng, lnb, b_pre, sbuf,
               blk & 31, blk >> 5, tid, gb4, lnH, lnM, lnL, red, smean, srstd);
    gridbar(barcnt, tid);
  }
  if (grp == 1 && ng < 64)
    ys_unit(sbuf, WOf, b_out, out, Ln, ng >> 3, ng & 7, tid, gb4);  // ys[L-1]
}

// ---------------- host ----------------

extern "C" void kernel_launch(void* const* d_in, const int* in_sizes, int n_in,
                              void* d_out, int out_size, void* d_ws, size_t ws_size,
                              hipStream_t stream) {
  const float* z     = (const float*)d_in[0];
  const float* W_l2h = (const float*)d_in[1];
  const float* b_l2h = (const float*)d_in[2];
  const float* W_l2c = (const float*)d_in[3];
  const float* b_l2c = (const float*)d_in[4];
  const float* W_zp  = (const float*)d_in[5];
  const float* b_zp  = (const float*)d_in[6];
  const float* W_ih0 = (const float*)d_in[7];
  const float* W_hh0 = (const float*)d_in[8];
  const float* b_ih0 = (const float*)d_in[9];
  const float* b_hh0 = (const float*)d_in[10];
  const float* W_ih1 = (const float*)d_in[11];
  const float* W_hh1 = (const float*)d_in[12];
  const float* b_ih1 = (const float*)d_in[13];
  const float* b_hh1 = (const float*)d_in[14];
  const float* ln_g  = (const float*)d_in[15];
  const float* ln_b  = (const float*)d_in[16];
  const float* W_pre = (const float*)d_in[17];
  const float* b_pre = (const float*)d_in[18];
  const float* W_out = (const float*)d_in[19];
  const float* b_out = (const float*)d_in[20];
  float* out = (float*)d_out;
  char* ws = (char*)d_ws;

  size_t off = 0;
  auto alloc = [&](size_t bytes) { void* p = ws + off; off += bytes; return p; };
  u16*   WAf  = (u16*)alloc(12582912);   // 3 planes x 2048x1024 bf16
  u16*   WBf  = (u16*)alloc(12582912);
  u16*   WPf  = (u16*)alloc(1572864);    // 3 x 512x512
  u16*   WOf  = (u16*)alloc(393216);     // 3 x 128x512
  float* GZ0  = (float*)alloc(1048576);
  float* GZ1  = (float*)alloc(1048576);
  float* gb1  = (float*)alloc(8192);
  float* zp   = (float*)alloc(262144);
  u16*   ha0  = (u16*)alloc(393216);     // 3 planes x 128x512
  u16*   ha1  = (u16*)alloc(393216);
  u16*   hb0  = (u16*)alloc(393216);
  u16*   hb1  = (u16*)alloc(393216);
  float* ca   = (float*)alloc(262144);
  float* cb   = (float*)alloc(262144);
  u16*   sbuf = (u16*)alloc(393216);
  uint32* barcnt = (uint32*)alloc(64);

  // allow >64KB dynamic LDS (idempotent; harmless if already set)
  static bool attr_set = false;
  if (!attr_set) {
    (void)hipFuncSetAttribute((const void*)persist_k,
                              hipFuncAttributeMaxDynamicSharedMemorySize, 153728);
    attr_set = true;
  }

  prep_hc0<<<512, 256, 0, stream>>>(z, W_l2h, b_l2h, W_l2c, b_l2c, ha0, hb0, ca, cb);
  prep_zp<<<256, 256, 0, stream>>>(z, W_zp, b_zp, zp);
  prep_gz<<<1024, 256, 0, stream>>>(zp, W_ih0, b_ih0, b_hh0, b_out, GZ0, GZ1);
  prep_waf<<<8192, 256, 0, stream>>>(W_out, W_ih0, W_hh0, WAf);
  prep_wbf<<<8192, 256, 0, stream>>>(W_ih1, W_hh1, WBf);
  prep_misc<<<2057, 256, 0, stream>>>(W_pre, W_out, b_ih1, b_hh1, WPf, WOf, gb1, sbuf, barcnt);

  persist_k<<<256, 256, 153728, stream>>>(WAf, WBf, WPf, WOf, GZ0, GZ1, gb1, ca, cb,
                                          ha0, ha1, hb0, hb1, sbuf,
                                          ln_g, ln_b, b_pre, b_out, out, barcnt);
}

// Round 7
// 28522.784 us; speedup vs baseline: 1.8936x; 1.8936x over previous
//
#include <hip/hip_runtime.h>

// TimeVAEDecoder: B=128, LAT=128, H=512, F=128, L=256, NL=2
// Round 7: R6 (LDS-resident weight slices, persistent, 3 barriers/step) +
//  (a) 1024-thread blocks: 16 waves = 4/SIMD occupancy (R6 had 1/SIMD; all
//      load latency exposed). Gates GEMM: wave=(mt,kh), partials in gb2[2][..].
//  (b) cheap grid barrier: RELAXED spin polls (no per-poll L2 invalidate!),
//      one ACQUIRE at the end. R5/R6 polled with ACQUIRE = continuous
//      all-XCD L2 invalidation -> weight/bias refetch storms.
// Numerics identical to R3-R6 (3-plane split, MFMA6, two-pass LN, 256-thread
// lnpre/ys bodies) -> absmax pedigree 0.066.

typedef unsigned int uint32;
typedef unsigned short u16;
typedef __attribute__((ext_vector_type(8))) short bf16x8;
typedef __attribute__((ext_vector_type(4))) float f32x4;

static constexpr int Ln = 256, Fn = 128;
static constexpr int APS = 65536;    // activation plane stride (elems): 128x512
static constexpr int WPS = 2097152;  // cell-weight plane stride: 2048x1024
static constexpr int OPS = 65536;    // W_out plane stride: 128x512
static constexpr int PPS = 262144;   // W_pre plane stride: 512x512

__device__ __forceinline__ u16 f2bf(float f) {
  union { float f; uint32 u; } v; v.f = f;
  uint32 u = v.u + 0x7fffu + ((v.u >> 16) & 1u);
  return (u16)(u >> 16);
}
__device__ __forceinline__ float bf2f(u16 h) {
  union { uint32 u; float f; } v; v.u = ((uint32)h) << 16;
  return v.f;
}
__device__ __forceinline__ void splitbf3(float v, u16* hi, u16* mid, u16* lo) {
  u16 h = f2bf(v);
  float r = v - bf2f(h);
  u16 m = f2bf(r);
  float r2 = r - bf2f(m);
  *hi = h; *mid = m; *lo = f2bf(r2);
}
__device__ __forceinline__ float sigm(float x) { return 1.f / (1.f + expf(-x)); }
__device__ __forceinline__ bf16x8 ldf(const u16* p) { return *(const bf16x8*)p; }

#define MFMA1(A, B, ACC) ACC = __builtin_amdgcn_mfma_f32_16x16x32_bf16((A), (B), (ACC), 0, 0, 0)
// 6 products, 4 accumulators: A0+=hh; A1+=hm+mh; A2+=hl+mm; A3+=lh
#define MFMA6(AH, AM, AL, BH, BM, BL, A0, A1, A2, A3) \
  do {                                                \
    MFMA1(AH, BH, A0);                                \
    MFMA1(AH, BM, A1); MFMA1(AM, BH, A1);             \
    MFMA1(AH, BL, A2); MFMA1(AM, BM, A2);             \
    MFMA1(AL, BH, A3);                                \
  } while (0)

// ---------------- prep kernels (unchanged) ----------------

__global__ void prep_hc0(const float* __restrict__ z,
                         const float* __restrict__ W_l2h, const float* __restrict__ b_l2h,
                         const float* __restrict__ W_l2c, const float* __restrict__ b_l2c,
                         u16* __restrict__ ha0, u16* __restrict__ hb0,
                         float* __restrict__ ca, float* __restrict__ cb) {
  int idx = blockIdx.x * 256 + threadIdx.x;  // 131072
  int b = idx & 127, j = idx >> 7;
  float ah = b_l2h[j], ac = b_l2c[j];
  for (int k = 0; k < 128; ++k) {
    float zv = z[b * 128 + k];
    ah += zv * W_l2h[j * 128 + k];
    ac += zv * W_l2c[j * 128 + k];
  }
  int flat = b * 1024 + j;
  if (flat < 65536) {
    splitbf3(ah, &ha0[flat], &ha0[APS + flat], &ha0[2 * APS + flat]);
    ca[flat] = ac;
  } else {
    flat -= 65536;
    splitbf3(ah, &hb0[flat], &hb0[APS + flat], &hb0[2 * APS + flat]);
    cb[flat] = ac;
  }
}

__global__ void prep_zp(const float* __restrict__ z, const float* __restrict__ W_zp,
                        const float* __restrict__ b_zp, float* __restrict__ zp) {
  int idx = blockIdx.x * 256 + threadIdx.x;  // 65536
  int b = idx & 127, h = idx >> 7;
  float a = b_zp[h];
  for (int k = 0; k < 128; ++k) a += z[b * 128 + k] * W_zp[h * 128 + k];
  zp[b * 512 + h] = a;
}

__global__ void prep_gz(const float* __restrict__ zp, const float* __restrict__ W_ih0,
                        const float* __restrict__ b_ih0, const float* __restrict__ b_hh0,
                        const float* __restrict__ b_out,
                        float* __restrict__ GZ0, float* __restrict__ GZ1) {
  int idx = blockIdx.x * 256 + threadIdx.x;  // 262144
  int b = idx & 127, g = idx >> 7;
  const float* wr = W_ih0 + (size_t)g * 640;
  float a = b_ih0[g] + b_hh0[g];
  for (int k = 0; k < 512; ++k) a += zp[b * 512 + k] * wr[128 + k];
  float co = 0.f;
  for (int f = 0; f < 128; ++f) co += b_out[f] * wr[f];
  GZ0[b * 2048 + g] = a;
  GZ1[b * 2048 + g] = a + co;
}

__global__ void prep_waf(const float* __restrict__ W_out, const float* __restrict__ W_ih0,
                         const float* __restrict__ W_hh0, u16* __restrict__ WAf) {
  int idx = blockIdx.x * 256 + threadIdx.x;  // 2097152
  int k = idx & 1023, g = idx >> 10;
  float v;
  if (k < 512) {
    v = 0.f;
    const float* wr = W_ih0 + (size_t)g * 640;
    for (int f = 0; f < 128; ++f) v += W_out[f * 512 + k] * wr[f];
  } else {
    v = W_hh0[(size_t)g * 512 + (k - 512)];
  }
  splitbf3(v, &WAf[idx], &WAf[WPS + idx], &WAf[2 * WPS + idx]);
}

__global__ void prep_wbf(const float* __restrict__ W_ih1, const float* __restrict__ W_hh1,
                         u16* __restrict__ WBf) {
  int idx = blockIdx.x * 256 + threadIdx.x;  // 2097152
  int k = idx & 1023, g = idx >> 10;
  float v = (k < 512) ? W_ih1[(size_t)g * 512 + k] : W_hh1[(size_t)g * 512 + (k - 512)];
  splitbf3(v, &WBf[idx], &WBf[WPS + idx], &WBf[2 * WPS + idx]);
}

__global__ void prep_misc(const float* __restrict__ W_pre, const float* __restrict__ W_out,
                          const float* __restrict__ b_ih1, const float* __restrict__ b_hh1,
                          u16* __restrict__ WPf, u16* __restrict__ WOf,
                          float* __restrict__ gb1, u16* __restrict__ s,
                          uint32* __restrict__ barcnt) {
  int idx = blockIdx.x * 256 + threadIdx.x;
  if (idx < 262144) { splitbf3(W_pre[idx], &WPf[idx], &WPf[PPS + idx], &WPf[2 * PPS + idx]); return; }
  idx -= 262144;
  if (idx < 65536) { splitbf3(W_out[idx], &WOf[idx], &WOf[OPS + idx], &WOf[2 * OPS + idx]); return; }
  idx -= 65536;
  if (idx < 2048) { gb1[idx] = b_ih1[idx] + b_hh1[idx]; return; }
  idx -= 2048;
  if (idx < 196608) { s[idx] = 0; return; }
  idx -= 196608;
  if (idx < 8) barcnt[idx] = 0;
}

// ---------------- persistent kernel ----------------

// Grid barrier: one RELEASE add, RELAXED spin (no per-poll invalidate),
// one ACQUIRE load at the end.
__device__ __forceinline__ void gridbar(uint32* cnt, int tid) {
  __syncthreads();
  if (tid == 0) {
    uint32 old = __hip_atomic_fetch_add(cnt, 1u, __ATOMIC_RELEASE, __HIP_MEMORY_SCOPE_AGENT);
    uint32 target = (old / 256u + 1u) * 256u;
    while (__hip_atomic_load(cnt, __ATOMIC_RELAXED, __HIP_MEMORY_SCOPE_AGENT) < target)
      __builtin_amdgcn_s_sleep(2);
    (void)__hip_atomic_load(cnt, __ATOMIC_ACQUIRE, __HIP_MEMORY_SCOPE_AGENT);
  }
  __syncthreads();
}

// Gates GEMM vs LDS-resident N=16 slice, 16 waves: wave=(mt=w&7, kh=w>>3).
// Each wave: M=16 (rows mt*16..), K=512 (its kh half), 16 kb-iters x 6 MFMA.
// Partials -> gb2[kh][128][17]; epilogue tid<512 sums kh0+kh1 + bias + cell.
__device__ __forceinline__ void gates2(
    const u16* __restrict__ x0, const u16* __restrict__ x1,
    const u16* wlds, const float* __restrict__ bias, int bias_stride,
    int ng, float& creg, u16* __restrict__ hout, int tid, float* gb2) {
  int lane = tid & 63, w = tid >> 6, q = lane >> 4, r16 = lane & 15;
  int mt = w & 7, kh = w >> 3;
  const u16* xs = kh ? x1 : x0;
  const u16* ar = xs + (size_t)(mt * 16 + r16) * 512 + q * 8;
  const u16* wb = wlds + (kh * 16) * 512 + lane * 8;
  f32x4 A0 = {0.f, 0.f, 0.f, 0.f}, A1 = A0, A2 = A0, A3 = A0;
#pragma unroll 8
  for (int kb = 0; kb < 16; ++kb) {
    const u16* bp = wb + kb * 512;
    bf16x8 bh = *(const bf16x8*)bp;
    bf16x8 bm = *(const bf16x8*)(bp + 16384);
    bf16x8 bl = *(const bf16x8*)(bp + 32768);
    const u16* pa = ar + kb * 32;
    bf16x8 ah = ldf(pa), am = ldf(pa + APS), al = ldf(pa + 2 * APS);
    MFMA6(ah, am, al, bh, bm, bl, A0, A1, A2, A3);
  }
#pragma unroll
  for (int r = 0; r < 4; ++r)
    gb2[(kh * 128 + mt * 16 + q * 4 + r) * 17 + r16] =
        ((A3[r] + A2[r]) + A1[r]) + A0[r];
  __syncthreads();
  if (tid < 512) {
    int b = tid >> 2, j = tid & 3;
    int h = ng * 4 + j;
    const float* bb = bias + (size_t)b * bias_stride;  // 2048 (GZ) or 0 (gb1)
    float gi = (gb2[(b)*17 + j * 4 + 0] + gb2[(128 + b) * 17 + j * 4 + 0]) + bb[h];
    float gf = (gb2[(b)*17 + j * 4 + 1] + gb2[(128 + b) * 17 + j * 4 + 1]) + bb[512 + h];
    float gc = (gb2[(b)*17 + j * 4 + 2] + gb2[(128 + b) * 17 + j * 4 + 2]) + bb[1024 + h];
    float go = (gb2[(b)*17 + j * 4 + 3] + gb2[(128 + b) * 17 + j * 4 + 3]) + bb[1536 + h];
    float cn = sigm(gf) * creg + sigm(gi) * tanhf(gc);
    creg = cn;
    float hv = sigm(go) * tanhf(cn);
    int idx = b * 512 + h;
    splitbf3(hv, &hout[idx], &hout[APS + idx], &hout[2 * APS + idx]);
  }
}

// ys tile: 16 rows x 16 f-cols, waves 0..3 split K=512, W_out from L2.
// (R6 256-thread body; waves 4..15 just hit the sync.)
__device__ __forceinline__ void ys_unit(
    const u16* __restrict__ sv, const u16* __restrict__ WOf,
    const float* __restrict__ b_out, float* __restrict__ ys,
    int t, int bg, int fh, int tid, float* gb4) {
  int lane = tid & 63, w = tid >> 6;
  int q = lane >> 4, r16 = lane & 15;
  int f0 = fh * 16, b0 = bg * 16;
  if (w < 4) {
    const u16* wr = WOf + (size_t)(f0 + r16) * 512 + w * 128 + q * 8;
    const u16* ar = sv + (size_t)(b0 + r16) * 512 + w * 128 + q * 8;
    f32x4 A0 = {0.f, 0.f, 0.f, 0.f}, A1 = A0, A2 = A0, A3 = A0;
#pragma unroll
    for (int kb = 0; kb < 4; ++kb) {
      bf16x8 ah = ldf(ar + kb * 32), am = ldf(ar + APS + kb * 32), al = ldf(ar + 2 * APS + kb * 32);
      bf16x8 bh = ldf(wr + kb * 32), bm = ldf(wr + OPS + kb * 32), bl = ldf(wr + 2 * OPS + kb * 32);
      MFMA6(ah, am, al, bh, bm, bl, A0, A1, A2, A3);
    }
#pragma unroll
    for (int r = 0; r < 4; ++r)
      gb4[(w * 16 + q * 4 + r) * 17 + r16] = ((A3[r] + A2[r]) + A1[r]) + A0[r];
  }
  __syncthreads();
  if (tid < 256) {
    int bl_ = tid >> 4, fl = tid & 15;
    float val = ((gb4[(3 * 16 + bl_) * 17 + fl] + gb4[(2 * 16 + bl_) * 17 + fl]) +
                 gb4[(1 * 16 + bl_) * 17 + fl]) + gb4[(0 * 16 + bl_) * 17 + fl] + b_out[f0 + fl];
    ys[(size_t)(b0 + bl_) * (Ln * Fn) + (size_t)(t - 1) * Fn + f0 + fl] = val;
  }
}

// LN(hb) -> pre = relu(ln@W_pre^T + b_pre) -> s = pre + ln (W_pre from L2)
// R6 256-thread body verbatim; tid>=256 only participates in syncs.
__device__ __forceinline__ void lnpre_unit(
    const u16* __restrict__ hb, const u16* __restrict__ WPf,
    const float* __restrict__ lng, const float* __restrict__ lnb,
    const float* __restrict__ b_pre, u16* __restrict__ s_out,
    int jg, int bg, int tid, float* gb4,
    u16* lnH, u16* lnM, u16* lnL, float* red, float* smean, float* srstd) {
  int lane = tid & 63, w = tid >> 6;
  int q = lane >> 4, r16 = lane & 15;
  int j0 = jg * 16, b0 = bg * 16;
  int rl = (tid >> 4) & 15, cg = tid & 15;
  bool act = tid < 256;
  float v[32];
  if (act) {
    const u16* hr = hb + (size_t)(b0 + rl) * 512 + cg * 32;
    float sm = 0.f;
#pragma unroll
    for (int kk = 0; kk < 32; ++kk) {
      v[kk] = (bf2f(hr[2 * APS + kk]) + bf2f(hr[APS + kk])) + bf2f(hr[kk]);
      sm += v[kk];
    }
    red[rl * 16 + cg] = sm;
  }
  __syncthreads();
  if (tid < 16) {
    float s1 = 0.f;
    for (int i = 0; i < 16; ++i) s1 += red[tid * 16 + i];
    smean[tid] = s1 * (1.f / 512.f);
  }
  __syncthreads();
  float m = act ? smean[rl] : 0.f;
  if (act) {
    float sq = 0.f;
#pragma unroll
    for (int kk = 0; kk < 32; ++kk) { float d = v[kk] - m; sq += d * d; }
    red[rl * 16 + cg] = sq;
  }
  __syncthreads();
  if (tid < 16) {
    float s2 = 0.f;
    for (int i = 0; i < 16; ++i) s2 += red[tid * 16 + i];
    srstd[tid] = 1.f / sqrtf(s2 * (1.f / 512.f) + 1e-5f);
  }
  __syncthreads();
  if (act) {
    float rs = srstd[rl];
#pragma unroll
    for (int kk = 0; kk < 32; ++kk) {
      int col = cg * 32 + kk;
      float lv = (v[kk] - m) * rs * lng[col] + lnb[col];
      splitbf3(lv, &lnH[rl * 520 + col], &lnM[rl * 520 + col], &lnL[rl * 520 + col]);
    }
  }
  __syncthreads();
  if (act) {
    const u16* wr = WPf + (size_t)(j0 + r16) * 512 + w * 128 + q * 8;
    const u16* aH = lnH + r16 * 520 + w * 128 + q * 8;
    const u16* aM = lnM + r16 * 520 + w * 128 + q * 8;
    const u16* aL = lnL + r16 * 520 + w * 128 + q * 8;
    f32x4 A0 = {0.f, 0.f, 0.f, 0.f}, A1 = A0, A2 = A0, A3 = A0;
#pragma unroll
    for (int kb = 0; kb < 4; ++kb) {
      bf16x8 ah = ldf(aH + kb * 32), am = ldf(aM + kb * 32), al = ldf(aL + kb * 32);
      bf16x8 bh = ldf(wr + kb * 32), bm = ldf(wr + PPS + kb * 32), bl = ldf(wr + 2 * PPS + kb * 32);
      MFMA6(ah, am, al, bh, bm, bl, A0, A1, A2, A3);
    }
#pragma unroll
    for (int r = 0; r < 4; ++r)
      gb4[(w * 16 + q * 4 + r) * 17 + r16] = ((A3[r] + A2[r]) + A1[r]) + A0[r];
  }
  __syncthreads();
  if (act) {
    int bl_ = tid >> 4, jl = tid & 15;
    int col = j0 + jl;
    float pre = ((gb4[(3 * 16 + bl_) * 17 + jl] + gb4[(2 * 16 + bl_) * 17 + jl]) +
                 gb4[(1 * 16 + bl_) * 17 + jl]) + gb4[(0 * 16 + bl_) * 17 + jl] + b_pre[col];
    pre = fmaxf(pre, 0.f);
    float lnv = (bf2f(lnL[bl_ * 520 + col]) + bf2f(lnM[bl_ * 520 + col])) + bf2f(lnH[bl_ * 520 + col]);
    float sval = pre + lnv;
    size_t sidx = (size_t)(b0 + bl_) * 512 + col;
    splitbf3(sval, &s_out[sidx], &s_out[APS + sidx], &s_out[2 * APS + sidx]);
  }
}

__global__ __launch_bounds__(1024, 2) void persist_k(
    const u16* __restrict__ WAf, const u16* __restrict__ WBf,
    const u16* __restrict__ WPf, const u16* __restrict__ WOf,
    const float* __restrict__ GZ0, const float* __restrict__ GZ1,
    const float* __restrict__ gb1,
    const float* __restrict__ ca, const float* __restrict__ cb,
    u16* ha0, u16* ha1, u16* hb0, u16* hb1, u16* sbuf,
    const float* __restrict__ lng, const float* __restrict__ lnb,
    const float* __restrict__ b_pre, const float* __restrict__ b_out,
    float* __restrict__ out, uint32* barcnt) {
  extern __shared__ char smem[];          // 153728 B total
  u16* wlds = (u16*)smem;                 // 96 KB: 3 planes x [kb 0..31][lane][8]
  char* ub = smem + 98304;                // phase union (55424 B)
  float* gb2 = (float*)ub;                // gates partials [2][128][17] f32 (17408 B)
  u16* lnH = (u16*)ub;                    // lnpre staging (aliases gb2)
  u16* lnM = lnH + 8320;
  u16* lnL = lnM + 8320;
  float* red = (float*)(ub + 49920);
  float* smean = (float*)(ub + 50944);
  float* srstd = (float*)(ub + 51008);
  float* gb4 = (float*)(ub + 51072);      // [4][16][17] f32
  int tid = threadIdx.x, blk = blockIdx.x;
  int grp = blk >> 7, ng = blk & 127;
  // stage this block's weight slice into LDS (lane-order, conflict-free)
  const u16* Wsrc = grp ? WBf : WAf;
  for (int i = tid; i < 49152; i += 1024) {
    int p = i >> 14, rem = i & 16383;
    int kb = rem >> 9, l2 = (rem >> 3) & 63, e = rem & 7;
    int q2 = l2 >> 4, r2 = l2 & 15;
    int grow = (r2 & 3) * 512 + ng * 4 + (r2 >> 2);  // gate-interleaved n
    wlds[i] = Wsrc[(size_t)p * WPS + (size_t)grow * 1024 + kb * 32 + q2 * 8 + e];
  }
  __syncthreads();
  // cell state: tid<512, one (b, h=ng*4+j) each
  float creg = 0.f;
  if (tid < 512) {
    const float* cs = grp ? cb : ca;
    creg = cs[(tid >> 2) * 512 + ng * 4 + (tid & 3)];
  }
  u16* haB[2] = {ha0, ha1};
  u16* hbB[2] = {hb0, hb1};
  for (int t = 0; t < Ln; ++t) {
    // phase A: cell0 blocks compute gates0([s||ha]); cell1 blocks 0..63 do ys[t-1]
    if (grp == 0) {
      gates2(sbuf, haB[t & 1], wlds, t ? GZ1 : GZ0, 2048, ng, creg,
             haB[(t + 1) & 1], tid, gb2);
    } else if (ng < 64 && t >= 1) {
      ys_unit(sbuf, WOf, b_out, out, t, ng >> 3, ng & 7, tid, gb4);
    }
    gridbar(barcnt, tid);
    // phase B: cell1 blocks compute gates1([ha'||hb])
    if (grp == 1) {
      gates2(haB[(t + 1) & 1], hbB[t & 1], wlds, gb1, 0, ng, creg,
             hbB[(t + 1) & 1], tid, gb2);
    }
    gridbar(barcnt, tid);
    // phase C: all 256 blocks: layernorm + pre + s'
    lnpre_unit(hbB[(t + 1) & 1], WPf, lng, lnb, b_pre, sbuf,
               blk & 31, blk >> 5, tid, gb4, lnH, lnM, lnL, red, smean, srstd);
    gridbar(barcnt, tid);
  }
  if (grp == 1 && ng < 64)
    ys_unit(sbuf, WOf, b_out, out, Ln, ng >> 3, ng & 7, tid, gb4);  // ys[L-1]
}

// ---------------- host ----------------

extern "C" void kernel_launch(void* const* d_in, const int* in_sizes, int n_in,
                              void* d_out, int out_size, void* d_ws, size_t ws_size,
                              hipStream_t stream) {
  const float* z     = (const float*)d_in[0];
  const float* W_l2h = (const float*)d_in[1];
  const float* b_l2h = (const float*)d_in[2];
  const float* W_l2c = (const float*)d_in[3];
  const float* b_l2c = (const float*)d_in[4];
  const float* W_zp  = (const float*)d_in[5];
  const float* b_zp  = (const float*)d_in[6];
  const float* W_ih0 = (const float*)d_in[7];
  const float* W_hh0 = (const float*)d_in[8];
  const float* b_ih0 = (const float*)d_in[9];
  const float* b_hh0 = (const float*)d_in[10];
  const float* W_ih1 = (const float*)d_in[11];
  const float* W_hh1 = (const float*)d_in[12];
  const float* b_ih1 = (const float*)d_in[13];
  const float* b_hh1 = (const float*)d_in[14];
  const float* ln_g  = (const float*)d_in[15];
  const float* ln_b  = (const float*)d_in[16];
  const float* W_pre = (const float*)d_in[17];
  const float* b_pre = (const float*)d_in[18];
  const float* W_out = (const float*)d_in[19];
  const float* b_out = (const float*)d_in[20];
  float* out = (float*)d_out;
  char* ws = (char*)d_ws;

  size_t off = 0;
  auto alloc = [&](size_t bytes) { void* p = ws + off; off += bytes; return p; };
  u16*   WAf  = (u16*)alloc(12582912);   // 3 planes x 2048x1024 bf16
  u16*   WBf  = (u16*)alloc(12582912);
  u16*   WPf  = (u16*)alloc(1572864);    // 3 x 512x512
  u16*   WOf  = (u16*)alloc(393216);     // 3 x 128x512
  float* GZ0  = (float*)alloc(1048576);
  float* GZ1  = (float*)alloc(1048576);
  float* gb1  = (float*)alloc(8192);
  float* zp   = (float*)alloc(262144);
  u16*   ha0  = (u16*)alloc(393216);     // 3 planes x 128x512
  u16*   ha1  = (u16*)alloc(393216);
  u16*   hb0  = (u16*)alloc(393216);
  u16*   hb1  = (u16*)alloc(393216);
  float* ca   = (float*)alloc(262144);
  float* cb   = (float*)alloc(262144);
  u16*   sbuf = (u16*)alloc(393216);
  uint32* barcnt = (uint32*)alloc(64);

  static bool attr_set = false;
  if (!attr_set) {
    (void)hipFuncSetAttribute((const void*)persist_k,
                              hipFuncAttributeMaxDynamicSharedMemorySize, 153728);
    attr_set = true;
  }

  prep_hc0<<<512, 256, 0, stream>>>(z, W_l2h, b_l2h, W_l2c, b_l2c, ha0, hb0, ca, cb);
  prep_zp<<<256, 256, 0, stream>>>(z, W_zp, b_zp, zp);
  prep_gz<<<1024, 256, 0, stream>>>(zp, W_ih0, b_ih0, b_hh0, b_out, GZ0, GZ1);
  prep_waf<<<8192, 256, 0, stream>>>(W_out, W_ih0, W_hh0, WAf);
  prep_wbf<<<8192, 256, 0, stream>>>(W_ih1, W_hh1, WBf);
  prep_misc<<<2057, 256, 0, stream>>>(W_pre, W_out, b_ih1, b_hh1, WPf, WOf, gb1, sbuf, barcnt);

  persist_k<<<256, 1024, 153728, stream>>>(WAf, WBf, WPf, WOf, GZ0, GZ1, gb1, ca, cb,
                                           ha0, ha1, hb0, hb1, sbuf,
                                           ln_g, ln_b, b_pre, b_out, out, barcnt);
}

// Round 8
// 23043.008 us; speedup vs baseline: 2.3439x; 1.2378x over previous
//
#include <hip/hip_runtime.h>

// TimeVAEDecoder: B=128, LAT=128, H=512, F=128, L=256, NL=2
// Round 8: R7 (LDS-resident weight slices, 1024-thr persistent, 16 waves) +
// HIERARCHICAL EPOCH BARRIER. R5-R7 all pinned at ~107-111 us/step with all
// pipes <3% busy: the single-counter grid barrier serializes 256 cross-die
// agent-scope RMWs (~37 us/barrier x 3/step = the whole step). New barrier:
// 16 padded leaf counters (parallel) -> root (16 serial) -> epoch done-flag
// broadcast; RELAXED spin + single final ACQUIRE. Release chain carried
// leaf->root->done via ACQ_REL RMWs.
// Numerics identical to R3-R7 (3-plane split, MFMA6, two-pass LN) ->
// absmax pedigree 0.066-0.070.

typedef unsigned int uint32;
typedef unsigned short u16;
typedef __attribute__((ext_vector_type(8))) short bf16x8;
typedef __attribute__((ext_vector_type(4))) float f32x4;

static constexpr int Ln = 256, Fn = 128;
static constexpr int APS = 65536;    // activation plane stride (elems): 128x512
static constexpr int WPS = 2097152;  // cell-weight plane stride: 2048x1024
static constexpr int OPS = 65536;    // W_out plane stride: 128x512
static constexpr int PPS = 262144;   // W_pre plane stride: 512x512

__device__ __forceinline__ u16 f2bf(float f) {
  union { float f; uint32 u; } v; v.f = f;
  uint32 u = v.u + 0x7fffu + ((v.u >> 16) & 1u);
  return (u16)(u >> 16);
}
__device__ __forceinline__ float bf2f(u16 h) {
  union { uint32 u; float f; } v; v.u = ((uint32)h) << 16;
  return v.f;
}
__device__ __forceinline__ void splitbf3(float v, u16* hi, u16* mid, u16* lo) {
  u16 h = f2bf(v);
  float r = v - bf2f(h);
  u16 m = f2bf(r);
  float r2 = r - bf2f(m);
  *hi = h; *mid = m; *lo = f2bf(r2);
}
__device__ __forceinline__ float sigm(float x) { return 1.f / (1.f + expf(-x)); }
__device__ __forceinline__ bf16x8 ldf(const u16* p) { return *(const bf16x8*)p; }

#define MFMA1(A, B, ACC) ACC = __builtin_amdgcn_mfma_f32_16x16x32_bf16((A), (B), (ACC), 0, 0, 0)
// 6 products, 4 accumulators: A0+=hh; A1+=hm+mh; A2+=hl+mm; A3+=lh
#define MFMA6(AH, AM, AL, BH, BM, BL, A0, A1, A2, A3) \
  do {                                                \
    MFMA1(AH, BH, A0);                                \
    MFMA1(AH, BM, A1); MFMA1(AM, BH, A1);             \
    MFMA1(AH, BL, A2); MFMA1(AM, BM, A2);             \
    MFMA1(AL, BH, A3);                                \
  } while (0)

// ---------------- prep kernels ----------------

__global__ void prep_hc0(const float* __restrict__ z,
                         const float* __restrict__ W_l2h, const float* __restrict__ b_l2h,
                         const float* __restrict__ W_l2c, const float* __restrict__ b_l2c,
                         u16* __restrict__ ha0, u16* __restrict__ hb0,
                         float* __restrict__ ca, float* __restrict__ cb) {
  int idx = blockIdx.x * 256 + threadIdx.x;  // 131072
  int b = idx & 127, j = idx >> 7;
  float ah = b_l2h[j], ac = b_l2c[j];
  for (int k = 0; k < 128; ++k) {
    float zv = z[b * 128 + k];
    ah += zv * W_l2h[j * 128 + k];
    ac += zv * W_l2c[j * 128 + k];
  }
  int flat = b * 1024 + j;
  if (flat < 65536) {
    splitbf3(ah, &ha0[flat], &ha0[APS + flat], &ha0[2 * APS + flat]);
    ca[flat] = ac;
  } else {
    flat -= 65536;
    splitbf3(ah, &hb0[flat], &hb0[APS + flat], &hb0[2 * APS + flat]);
    cb[flat] = ac;
  }
}

__global__ void prep_zp(const float* __restrict__ z, const float* __restrict__ W_zp,
                        const float* __restrict__ b_zp, float* __restrict__ zp) {
  int idx = blockIdx.x * 256 + threadIdx.x;  // 65536
  int b = idx & 127, h = idx >> 7;
  float a = b_zp[h];
  for (int k = 0; k < 128; ++k) a += z[b * 128 + k] * W_zp[h * 128 + k];
  zp[b * 512 + h] = a;
}

__global__ void prep_gz(const float* __restrict__ zp, const float* __restrict__ W_ih0,
                        const float* __restrict__ b_ih0, const float* __restrict__ b_hh0,
                        const float* __restrict__ b_out,
                        float* __restrict__ GZ0, float* __restrict__ GZ1) {
  int idx = blockIdx.x * 256 + threadIdx.x;  // 262144
  int b = idx & 127, g = idx >> 7;
  const float* wr = W_ih0 + (size_t)g * 640;
  float a = b_ih0[g] + b_hh0[g];
  for (int k = 0; k < 512; ++k) a += zp[b * 512 + k] * wr[128 + k];
  float co = 0.f;
  for (int f = 0; f < 128; ++f) co += b_out[f] * wr[f];
  GZ0[b * 2048 + g] = a;
  GZ1[b * 2048 + g] = a + co;
}

__global__ void prep_waf(const float* __restrict__ W_out, const float* __restrict__ W_ih0,
                         const float* __restrict__ W_hh0, u16* __restrict__ WAf) {
  int idx = blockIdx.x * 256 + threadIdx.x;  // 2097152
  int k = idx & 1023, g = idx >> 10;
  float v;
  if (k < 512) {
    v = 0.f;
    const float* wr = W_ih0 + (size_t)g * 640;
    for (int f = 0; f < 128; ++f) v += W_out[f * 512 + k] * wr[f];
  } else {
    v = W_hh0[(size_t)g * 512 + (k - 512)];
  }
  splitbf3(v, &WAf[idx], &WAf[WPS + idx], &WAf[2 * WPS + idx]);
}

__global__ void prep_wbf(const float* __restrict__ W_ih1, const float* __restrict__ W_hh1,
                         u16* __restrict__ WBf) {
  int idx = blockIdx.x * 256 + threadIdx.x;  // 2097152
  int k = idx & 1023, g = idx >> 10;
  float v = (k < 512) ? W_ih1[(size_t)g * 512 + k] : W_hh1[(size_t)g * 512 + (k - 512)];
  splitbf3(v, &WBf[idx], &WBf[WPS + idx], &WBf[2 * WPS + idx]);
}

__global__ void prep_misc(const float* __restrict__ W_pre, const float* __restrict__ W_out,
                          const float* __restrict__ b_ih1, const float* __restrict__ b_hh1,
                          u16* __restrict__ WPf, u16* __restrict__ WOf,
                          float* __restrict__ gb1, u16* __restrict__ s,
                          uint32* __restrict__ barcnt) {
  int idx = blockIdx.x * 256 + threadIdx.x;
  if (idx < 262144) { splitbf3(W_pre[idx], &WPf[idx], &WPf[PPS + idx], &WPf[2 * PPS + idx]); return; }
  idx -= 262144;
  if (idx < 65536) { splitbf3(W_out[idx], &WOf[idx], &WOf[OPS + idx], &WOf[2 * OPS + idx]); return; }
  idx -= 65536;
  if (idx < 2048) { gb1[idx] = b_ih1[idx] + b_hh1[idx]; return; }
  idx -= 2048;
  if (idx < 196608) { s[idx] = 0; return; }
  idx -= 196608;
  if (idx < 1024) barcnt[idx] = 0;  // 16 leaves + root + done (padded lines)
}

// ---------------- persistent kernel ----------------

// Hierarchical epoch barrier: 16 padded leaf counters (16 blocks each, adds
// parallel across lines) -> root (16 serial adds) -> done := epoch (release).
// Spin RELAXED on done; one final ACQUIRE. Release chain: leaf/root RMWs are
// ACQ_REL so each completer carries all prior releases forward.
__device__ __forceinline__ void gridbar(uint32* bar, int tid, int blk, uint32 epoch) {
  __syncthreads();
  if (tid == 0) {
    uint32* leaf = bar + (size_t)(blk & 15) * 32;  // 128B-padded lines
    uint32* root = bar + 512;
    uint32* done = bar + 544;
    uint32 old = __hip_atomic_fetch_add(leaf, 1u, __ATOMIC_ACQ_REL, __HIP_MEMORY_SCOPE_AGENT);
    if ((old & 15u) == 15u) {
      uint32 ro = __hip_atomic_fetch_add(root, 1u, __ATOMIC_ACQ_REL, __HIP_MEMORY_SCOPE_AGENT);
      if ((ro & 15u) == 15u)
        __hip_atomic_store(done, epoch, __ATOMIC_RELEASE, __HIP_MEMORY_SCOPE_AGENT);
    }
    while (__hip_atomic_load(done, __ATOMIC_RELAXED, __HIP_MEMORY_SCOPE_AGENT) < epoch)
      __builtin_amdgcn_s_sleep(1);
    (void)__hip_atomic_load(done, __ATOMIC_ACQUIRE, __HIP_MEMORY_SCOPE_AGENT);
  }
  __syncthreads();
}

// Gates GEMM vs LDS-resident N=16 slice, 16 waves: wave=(mt=w&7, kh=w>>3).
// Each wave: M=16 (rows mt*16..), K=512 (its kh half), 16 kb-iters x 6 MFMA.
// Partials -> gb2[kh][128][17]; epilogue tid<512 sums kh0+kh1 + bias + cell.
__device__ __forceinline__ void gates2(
    const u16* __restrict__ x0, const u16* __restrict__ x1,
    const u16* wlds, const float* __restrict__ bias, int bias_stride,
    int ng, float& creg, u16* __restrict__ hout, int tid, float* gb2) {
  int lane = tid & 63, w = tid >> 6, q = lane >> 4, r16 = lane & 15;
  int mt = w & 7, kh = w >> 3;
  const u16* xs = kh ? x1 : x0;
  const u16* ar = xs + (size_t)(mt * 16 + r16) * 512 + q * 8;
  const u16* wb = wlds + (kh * 16) * 512 + lane * 8;
  f32x4 A0 = {0.f, 0.f, 0.f, 0.f}, A1 = A0, A2 = A0, A3 = A0;
#pragma unroll 8
  for (int kb = 0; kb < 16; ++kb) {
    const u16* bp = wb + kb * 512;
    bf16x8 bh = *(const bf16x8*)bp;
    bf16x8 bm = *(const bf16x8*)(bp + 16384);
    bf16x8 bl = *(const bf16x8*)(bp + 32768);
    const u16* pa = ar + kb * 32;
    bf16x8 ah = ldf(pa), am = ldf(pa + APS), al = ldf(pa + 2 * APS);
    MFMA6(ah, am, al, bh, bm, bl, A0, A1, A2, A3);
  }
#pragma unroll
  for (int r = 0; r < 4; ++r)
    gb2[(kh * 128 + mt * 16 + q * 4 + r) * 17 + r16] =
        ((A3[r] + A2[r]) + A1[r]) + A0[r];
  __syncthreads();
  if (tid < 512) {
    int b = tid >> 2, j = tid & 3;
    int h = ng * 4 + j;
    const float* bb = bias + (size_t)b * bias_stride;  // 2048 (GZ) or 0 (gb1)
    float gi = (gb2[(b)*17 + j * 4 + 0] + gb2[(128 + b) * 17 + j * 4 + 0]) + bb[h];
    float gf = (gb2[(b)*17 + j * 4 + 1] + gb2[(128 + b) * 17 + j * 4 + 1]) + bb[512 + h];
    float gc = (gb2[(b)*17 + j * 4 + 2] + gb2[(128 + b) * 17 + j * 4 + 2]) + bb[1024 + h];
    float go = (gb2[(b)*17 + j * 4 + 3] + gb2[(128 + b) * 17 + j * 4 + 3]) + bb[1536 + h];
    float cn = sigm(gf) * creg + sigm(gi) * tanhf(gc);
    creg = cn;
    float hv = sigm(go) * tanhf(cn);
    int idx = b * 512 + h;
    splitbf3(hv, &hout[idx], &hout[APS + idx], &hout[2 * APS + idx]);
  }
}

// ys tile: 16 rows x 16 f-cols, waves 0..3 split K=512, W_out from L2.
__device__ __forceinline__ void ys_unit(
    const u16* __restrict__ sv, const u16* __restrict__ WOf,
    const float* __restrict__ b_out, float* __restrict__ ys,
    int t, int bg, int fh, int tid, float* gb4) {
  int lane = tid & 63, w = tid >> 6;
  int q = lane >> 4, r16 = lane & 15;
  int f0 = fh * 16, b0 = bg * 16;
  if (w < 4) {
    const u16* wr = WOf + (size_t)(f0 + r16) * 512 + w * 128 + q * 8;
    const u16* ar = sv + (size_t)(b0 + r16) * 512 + w * 128 + q * 8;
    f32x4 A0 = {0.f, 0.f, 0.f, 0.f}, A1 = A0, A2 = A0, A3 = A0;
#pragma unroll
    for (int kb = 0; kb < 4; ++kb) {
      bf16x8 ah = ldf(ar + kb * 32), am = ldf(ar + APS + kb * 32), al = ldf(ar + 2 * APS + kb * 32);
      bf16x8 bh = ldf(wr + kb * 32), bm = ldf(wr + OPS + kb * 32), bl = ldf(wr + 2 * OPS + kb * 32);
      MFMA6(ah, am, al, bh, bm, bl, A0, A1, A2, A3);
    }
#pragma unroll
    for (int r = 0; r < 4; ++r)
      gb4[(w * 16 + q * 4 + r) * 17 + r16] = ((A3[r] + A2[r]) + A1[r]) + A0[r];
  }
  __syncthreads();
  if (tid < 256) {
    int bl_ = tid >> 4, fl = tid & 15;
    float val = ((gb4[(3 * 16 + bl_) * 17 + fl] + gb4[(2 * 16 + bl_) * 17 + fl]) +
                 gb4[(1 * 16 + bl_) * 17 + fl]) + gb4[(0 * 16 + bl_) * 17 + fl] + b_out[f0 + fl];
    ys[(size_t)(b0 + bl_) * (Ln * Fn) + (size_t)(t - 1) * Fn + f0 + fl] = val;
  }
}

// LN(hb) -> pre = relu(ln@W_pre^T + b_pre) -> s = pre + ln (W_pre from L2)
__device__ __forceinline__ void lnpre_unit(
    const u16* __restrict__ hb, const u16* __restrict__ WPf,
    const float* __restrict__ lng, const float* __restrict__ lnb,
    const float* __restrict__ b_pre, u16* __restrict__ s_out,
    int jg, int bg, int tid, float* gb4,
    u16* lnH, u16* lnM, u16* lnL, float* red, float* smean, float* srstd) {
  int lane = tid & 63, w = tid >> 6;
  int q = lane >> 4, r16 = lane & 15;
  int j0 = jg * 16, b0 = bg * 16;
  int rl = (tid >> 4) & 15, cg = tid & 15;
  bool act = tid < 256;
  float v[32];
  if (act) {
    const u16* hr = hb + (size_t)(b0 + rl) * 512 + cg * 32;
    float sm = 0.f;
#pragma unroll
    for (int kk = 0; kk < 32; ++kk) {
      v[kk] = (bf2f(hr[2 * APS + kk]) + bf2f(hr[APS + kk])) + bf2f(hr[kk]);
      sm += v[kk];
    }
    red[rl * 16 + cg] = sm;
  }
  __syncthreads();
  if (tid < 16) {
    float s1 = 0.f;
    for (int i = 0; i < 16; ++i) s1 += red[tid * 16 + i];
    smean[tid] = s1 * (1.f / 512.f);
  }
  __syncthreads();
  float m = act ? smean[rl] : 0.f;
  if (act) {
    float sq = 0.f;
#pragma unroll
    for (int kk = 0; kk < 32; ++kk) { float d = v[kk] - m; sq += d * d; }
    red[rl * 16 + cg] = sq;
  }
  __syncthreads();
  if (tid < 16) {
    float s2 = 0.f;
    for (int i = 0; i < 16; ++i) s2 += red[tid * 16 + i];
    srstd[tid] = 1.f / sqrtf(s2 * (1.f / 512.f) + 1e-5f);
  }
  __syncthreads();
  if (act) {
    float rs = srstd[rl];
#pragma unroll
    for (int kk = 0; kk < 32; ++kk) {
      int col = cg * 32 + kk;
      float lv = (v[kk] - m) * rs * lng[col] + lnb[col];
      splitbf3(lv, &lnH[rl * 520 + col], &lnM[rl * 520 + col], &lnL[rl * 520 + col]);
    }
  }
  __syncthreads();
  if (act) {
    const u16* wr = WPf + (size_t)(j0 + r16) * 512 + w * 128 + q * 8;
    const u16* aH = lnH + r16 * 520 + w * 128 + q * 8;
    const u16* aM = lnM + r16 * 520 + w * 128 + q * 8;
    const u16* aL = lnL + r16 * 520 + w * 128 + q * 8;
    f32x4 A0 = {0.f, 0.f, 0.f, 0.f}, A1 = A0, A2 = A0, A3 = A0;
#pragma unroll
    for (int kb = 0; kb < 4; ++kb) {
      bf16x8 ah = ldf(aH + kb * 32), am = ldf(aM + kb * 32), al = ldf(aL + kb * 32);
      bf16x8 bh = ldf(wr + kb * 32), bm = ldf(wr + PPS + kb * 32), bl = ldf(wr + 2 * PPS + kb * 32);
      MFMA6(ah, am, al, bh, bm, bl, A0, A1, A2, A3);
    }
#pragma unroll
    for (int r = 0; r < 4; ++r)
      gb4[(w * 16 + q * 4 + r) * 17 + r16] = ((A3[r] + A2[r]) + A1[r]) + A0[r];
  }
  __syncthreads();
  if (act) {
    int bl_ = tid >> 4, jl = tid & 15;
    int col = j0 + jl;
    float pre = ((gb4[(3 * 16 + bl_) * 17 + jl] + gb4[(2 * 16 + bl_) * 17 + jl]) +
                 gb4[(1 * 16 + bl_) * 17 + jl]) + gb4[(0 * 16 + bl_) * 17 + jl] + b_pre[col];
    pre = fmaxf(pre, 0.f);
    float lnv = (bf2f(lnL[bl_ * 520 + col]) + bf2f(lnM[bl_ * 520 + col])) + bf2f(lnH[bl_ * 520 + col]);
    float sval = pre + lnv;
    size_t sidx = (size_t)(b0 + bl_) * 512 + col;
    splitbf3(sval, &s_out[sidx], &s_out[APS + sidx], &s_out[2 * APS + sidx]);
  }
}

__global__ __launch_bounds__(1024, 2) void persist_k(
    const u16* __restrict__ WAf, const u16* __restrict__ WBf,
    const u16* __restrict__ WPf, const u16* __restrict__ WOf,
    const float* __restrict__ GZ0, const float* __restrict__ GZ1,
    const float* __restrict__ gb1,
    const float* __restrict__ ca, const float* __restrict__ cb,
    u16* ha0, u16* ha1, u16* hb0, u16* hb1, u16* sbuf,
    const float* __restrict__ lng, const float* __restrict__ lnb,
    const float* __restrict__ b_pre, const float* __restrict__ b_out,
    float* __restrict__ out, uint32* barcnt) {
  extern __shared__ char smem[];          // 153728 B total
  u16* wlds = (u16*)smem;                 // 96 KB: 3 planes x [kb 0..31][lane][8]
  char* ub = smem + 98304;                // phase union (55424 B)
  float* gb2 = (float*)ub;                // gates partials [2][128][17] f32
  u16* lnH = (u16*)ub;                    // lnpre staging (aliases gb2)
  u16* lnM = lnH + 8320;
  u16* lnL = lnM + 8320;
  float* red = (float*)(ub + 49920);
  float* smean = (float*)(ub + 50944);
  float* srstd = (float*)(ub + 51008);
  float* gb4 = (float*)(ub + 51072);      // [4][16][17] f32
  int tid = threadIdx.x, blk = blockIdx.x;
  int grp = blk >> 7, ng = blk & 127;
  // stage this block's weight slice into LDS (lane-order, conflict-free)
  const u16* Wsrc = grp ? WBf : WAf;
  for (int i = tid; i < 49152; i += 1024) {
    int p = i >> 14, rem = i & 16383;
    int kb = rem >> 9, l2 = (rem >> 3) & 63, e = rem & 7;
    int q2 = l2 >> 4, r2 = l2 & 15;
    int grow = (r2 & 3) * 512 + ng * 4 + (r2 >> 2);  // gate-interleaved n
    wlds[i] = Wsrc[(size_t)p * WPS + (size_t)grow * 1024 + kb * 32 + q2 * 8 + e];
  }
  __syncthreads();
  // cell state: tid<512, one (b, h=ng*4+j) each
  float creg = 0.f;
  if (tid < 512) {
    const float* cs = grp ? cb : ca;
    creg = cs[(tid >> 2) * 512 + ng * 4 + (tid & 3)];
  }
  u16* haB[2] = {ha0, ha1};
  u16* hbB[2] = {hb0, hb1};
  for (int t = 0; t < Ln; ++t) {
    // phase A: cell0 blocks compute gates0([s||ha]); cell1 blocks 0..63 do ys[t-1]
    if (grp == 0) {
      gates2(sbuf, haB[t & 1], wlds, t ? GZ1 : GZ0, 2048, ng, creg,
             haB[(t + 1) & 1], tid, gb2);
    } else if (ng < 64 && t >= 1) {
      ys_unit(sbuf, WOf, b_out, out, t, ng >> 3, ng & 7, tid, gb4);
    }
    gridbar(barcnt, tid, blk, 3u * t + 1u);
    // phase B: cell1 blocks compute gates1([ha'||hb])
    if (grp == 1) {
      gates2(haB[(t + 1) & 1], hbB[t & 1], wlds, gb1, 0, ng, creg,
             hbB[(t + 1) & 1], tid, gb2);
    }
    gridbar(barcnt, tid, blk, 3u * t + 2u);
    // phase C: all 256 blocks: layernorm + pre + s'
    lnpre_unit(hbB[(t + 1) & 1], WPf, lng, lnb, b_pre, sbuf,
               blk & 31, blk >> 5, tid, gb4, lnH, lnM, lnL, red, smean, srstd);
    gridbar(barcnt, tid, blk, 3u * t + 3u);
  }
  if (grp == 1 && ng < 64)
    ys_unit(sbuf, WOf, b_out, out, Ln, ng >> 3, ng & 7, tid, gb4);  // ys[L-1]
}

// ---------------- host ----------------

extern "C" void kernel_launch(void* const* d_in, const int* in_sizes, int n_in,
                              void* d_out, int out_size, void* d_ws, size_t ws_size,
                              hipStream_t stream) {
  const float* z     = (const float*)d_in[0];
  const float* W_l2h = (const float*)d_in[1];
  const float* b_l2h = (const float*)d_in[2];
  const float* W_l2c = (const float*)d_in[3];
  const float* b_l2c = (const float*)d_in[4];
  const float* W_zp  = (const float*)d_in[5];
  const float* b_zp  = (const float*)d_in[6];
  const float* W_ih0 = (const float*)d_in[7];
  const float* W_hh0 = (const float*)d_in[8];
  const float* b_ih0 = (const float*)d_in[9];
  const float* b_hh0 = (const float*)d_in[10];
  const float* W_ih1 = (const float*)d_in[11];
  const float* W_hh1 = (const float*)d_in[12];
  const float* b_ih1 = (const float*)d_in[13];
  const float* b_hh1 = (const float*)d_in[14];
  const float* ln_g  = (const float*)d_in[15];
  const float* ln_b  = (const float*)d_in[16];
  const float* W_pre = (const float*)d_in[17];
  const float* b_pre = (const float*)d_in[18];
  const float* W_out = (const float*)d_in[19];
  const float* b_out = (const float*)d_in[20];
  float* out = (float*)d_out;
  char* ws = (char*)d_ws;

  size_t off = 0;
  auto alloc = [&](size_t bytes) { void* p = ws + off; off += bytes; return p; };
  u16*   WAf  = (u16*)alloc(12582912);   // 3 planes x 2048x1024 bf16
  u16*   WBf  = (u16*)alloc(12582912);
  u16*   WPf  = (u16*)alloc(1572864);    // 3 x 512x512
  u16*   WOf  = (u16*)alloc(393216);     // 3 x 128x512
  float* GZ0  = (float*)alloc(1048576);
  float* GZ1  = (float*)alloc(1048576);
  float* gb1  = (float*)alloc(8192);
  float* zp   = (float*)alloc(262144);
  u16*   ha0  = (u16*)alloc(393216);     // 3 planes x 128x512
  u16*   ha1  = (u16*)alloc(393216);
  u16*   hb0  = (u16*)alloc(393216);
  u16*   hb1  = (u16*)alloc(393216);
  float* ca   = (float*)alloc(262144);
  float* cb   = (float*)alloc(262144);
  u16*   sbuf = (u16*)alloc(393216);
  uint32* barcnt = (uint32*)alloc(4096); // 16 leaves(x32) + root + done, padded

  static bool attr_set = false;
  if (!attr_set) {
    (void)hipFuncSetAttribute((const void*)persist_k,
                              hipFuncAttributeMaxDynamicSharedMemorySize, 153728);
    attr_set = true;
  }

  prep_hc0<<<512, 256, 0, stream>>>(z, W_l2h, b_l2h, W_l2c, b_l2c, ha0, hb0, ca, cb);
  prep_zp<<<256, 256, 0, stream>>>(z, W_zp, b_zp, zp);
  prep_gz<<<1024, 256, 0, stream>>>(zp, W_ih0, b_ih0, b_hh0, b_out, GZ0, GZ1);
  prep_waf<<<8192, 256, 0, stream>>>(W_out, W_ih0, W_hh0, WAf);
  prep_wbf<<<8192, 256, 0, stream>>>(W_ih1, W_hh1, WBf);
  prep_misc<<<2061, 256, 0, stream>>>(W_pre, W_out, b_ih1, b_hh1, WPf, WOf, gb1, sbuf, barcnt);

  persist_k<<<256, 1024, 153728, stream>>>(WAf, WBf, WPf, WOf, GZ0, GZ1, gb1, ca, cb,
                                           ha0, ha1, hb0, hb1, sbuf,
                                           ln_g, ln_b, b_pre, b_out, out, barcnt);
}